// Round 10
// baseline (123.388 us; speedup 1.0000x reference)
//
#include <hip/hip_runtime.h>
#include <math.h>

#define HH 4096
#define OO 4096
#define MAXLEN 2048

typedef float f4 __attribute__((ext_vector_type(4)));

__device__ inline float wave_sum(float v) {
#pragma unroll
    for (int off = 32; off; off >>= 1) v += __shfl_down(v, off, 64);
    return v;
}
__device__ inline float wave_max(float v) {
#pragma unroll
    for (int off = 32; off; off >>= 1) v = fmaxf(v, __shfl_down(v, off, 64));
    return v;
}

// sum 256 per-thread partials; result valid in all threads
__device__ inline float block_sum(float acc) {
    __shared__ float red[4];
    acc = wave_sum(acc);
    int t = threadIdx.x;
    if ((t & 63) == 0) red[t >> 6] = acc;
    __syncthreads();
    return red[0] + red[1] + red[2] + red[3];
}

// per-thread partial dot over 1024*NV floats; 256 threads/block.
// NT: non-temporal (stream-once) hint on the W side only.
template <int NV, bool NT>
__device__ inline float dot_row(const f4* __restrict__ W4, const f4* __restrict__ x4) {
    int t = threadIdx.x;
    float acc = 0.f;
#pragma unroll
    for (int j = 0; j < NV; ++j) {
        f4 w = NT ? __builtin_nontemporal_load(W4 + t + 256 * j) : W4[t + 256 * j];
        f4 v = x4[t + 256 * j];
        acc = fmaf(w[0], v[0], acc);
        acc = fmaf(w[1], v[1], acc);
        acc = fmaf(w[2], v[2], acc);
        acc = fmaf(w[3], v[3], acc);
    }
    return acc;
}

// fused first stage, 18432 = 9*2048 blocks, interleaved 1:6:2 —
//   m==0   -> attention logit row k            (att_W nt, 2 passes)
//   m=1..6 -> gh row k*6+m-1 = W_hh·h + b_hh   (W_hh non-nt, L3-resident)
//   m=7..8 -> atcemb row k*2+m-7 = atc_W[r,:H]·emb + atc_b  (nt)
__global__ void k_stage1(const float* __restrict__ att_W, const float* __restrict__ att_b,
                         const float* __restrict__ emb_W, const int* __restrict__ idx,
                         const float* __restrict__ hidden,
                         const float* __restrict__ W_hh, const float* __restrict__ b_hh,
                         const float* __restrict__ atc_W, const float* __restrict__ atc_b,
                         float* __restrict__ attlog, float* __restrict__ gh,
                         float* __restrict__ atcemb) {
    int blk = blockIdx.x;
    int k = blk / 9, m = blk % 9;
    if (m == 0) {
        int r = k;                         // 0..2047
        const float* emb = emb_W + (size_t)idx[0] * HH;
        const float* Wr = att_W + (size_t)r * (2 * HH);
        float acc = dot_row<4, true>((const f4*)Wr, (const f4*)emb)
                  + dot_row<4, true>((const f4*)(Wr + HH), (const f4*)hidden);
        float tot = block_sum(acc);
        if (threadIdx.x == 0) attlog[r] = tot + att_b[r];
    } else if (m <= 6) {
        int r = k * 6 + (m - 1);           // 0..12287
        float acc = dot_row<4, false>((const f4*)(W_hh + (size_t)r * HH), (const f4*)hidden);
        float tot = block_sum(acc);
        if (threadIdx.x == 0) gh[r] = tot + b_hh[r];
    } else {
        int r = k * 2 + (m - 7);           // 0..4095
        const float* emb = emb_W + (size_t)idx[0] * HH;
        float acc = dot_row<4, true>((const f4*)(atc_W + (size_t)r * (2 * HH)), (const f4*)emb);
        float tot = block_sum(acc);
        if (threadIdx.x == 0) atcemb[r] = tot + atc_b[r];
    }
}

// fused softmax + FULL weighted column-sum (merges old smpart + red).
// 256 blocks; block b owns f4-columns [4b, 4b+4) of atap and streams ALL
// 2048 enc rows for that slice (enc L3-resident, non-nt). Softmax weights
// computed once into LDS (identical order in every block -> deterministic).
// Block b also writes atw[8b..8b+8) (third output).
__global__ void k_atap(const float* __restrict__ attlog, const float* __restrict__ E,
                       float* __restrict__ atap, float* __restrict__ atw) {
    __shared__ float red[4];
    __shared__ float s_mx, s_sum;
    __shared__ float wl[MAXLEN];          // 8 KB softmax weights
    __shared__ f4 sarr[256];              // 4 KB partial sums
    int t = threadIdx.x;
    int b = blockIdx.x;                   // 0..255

    // softmax stats over all 2048 logits (fixed order)
    float v[8];
    float m = -INFINITY;
#pragma unroll
    for (int j = 0; j < 8; ++j) { v[j] = attlog[t + 256 * j]; m = fmaxf(m, v[j]); }
    m = wave_max(m);
    if ((t & 63) == 0) red[t >> 6] = m;
    __syncthreads();
    if (t == 0) s_mx = fmaxf(fmaxf(red[0], red[1]), fmaxf(red[2], red[3]));
    __syncthreads();
    float mx = s_mx;
    float s = 0.f;
#pragma unroll
    for (int j = 0; j < 8; ++j) s += expf(v[j] - mx);
    s = wave_sum(s);
    __syncthreads();
    if ((t & 63) == 0) red[t >> 6] = s;
    __syncthreads();
    if (t == 0) s_sum = red[0] + red[1] + red[2] + red[3];
    __syncthreads();
    float inv = 1.0f / s_sum;
#pragma unroll
    for (int j = 0; j < 8; ++j) wl[t + 256 * j] = expf(v[j] - mx) * inv;
    __syncthreads();

    // weighted column sums: thread (rg = t>>2, j = t&3) accumulates rows
    // rg + 64*i (i ascending, fixed order) of f4-column 4b + j.
    int j = t & 3, rg = t >> 2;           // rg 0..63
    const f4* E4 = (const f4*)E;
    f4 acc = {0.f, 0.f, 0.f, 0.f};
#pragma unroll 4
    for (int i = 0; i < 32; ++i) {
        int row = rg + 64 * i;
        float wm = wl[row];
        f4 e = E4[(size_t)row * (HH / 4) + b * 4 + j];
        acc[0] = fmaf(wm, e[0], acc[0]);
        acc[1] = fmaf(wm, e[1], acc[1]);
        acc[2] = fmaf(wm, e[2], acc[2]);
        acc[3] = fmaf(wm, e[3], acc[3]);
    }
    sarr[t] = acc;
    __syncthreads();
    // reduce over rg (fixed tree order)
#pragma unroll
    for (int off = 32; off; off >>= 1) {
        if (rg < off) sarr[rg * 4 + j] += sarr[(rg + off) * 4 + j];
        __syncthreads();
    }
    if (t < 4) ((f4*)atap)[b * 4 + t] = sarr[t];
    if (t < 8) atw[b * 8 + t] = wl[b * 8 + t];
}

// x = relu(atcemb + atc_W[r, H:2H]·atap), block per row, 16KB/block (nt)
__global__ void k_atc2(const float* __restrict__ atc_W, const float* __restrict__ atcemb,
                       const float* __restrict__ atap, float* __restrict__ x) {
    int r = blockIdx.x;
    float acc = dot_row<4, true>((const f4*)(atc_W + (size_t)r * (2 * HH) + HH),
                                 (const f4*)atap);
    float tot = block_sum(acc);
    if (threadIdx.x == 0) x[r] = fmaxf(tot + atcemb[r], 0.f);
}

// gi + gate math: block r computes 3 W_ih row-dots vs x (nt), combines with
// precomputed gh (already includes b_hh) -> h_new[r].
__global__ void k_gig(const float* __restrict__ W_ih, const float* __restrict__ b_ih,
                      const float* __restrict__ x, const float* __restrict__ gh,
                      const float* __restrict__ h, float* __restrict__ h_new) {
    __shared__ float red[3][4];
    int r = blockIdx.x;
    int t = threadIdx.x, wid = t >> 6, lane = t & 63;
    const f4* xv = (const f4*)x;
    float a[3];
    a[0] = dot_row<4, true>((const f4*)(W_ih + (size_t)r * HH), xv);
    a[1] = dot_row<4, true>((const f4*)(W_ih + (size_t)(HH + r) * HH), xv);
    a[2] = dot_row<4, true>((const f4*)(W_ih + (size_t)(2 * HH + r) * HH), xv);
#pragma unroll
    for (int k = 0; k < 3; ++k) {
        float s = wave_sum(a[k]);
        if (lane == 0) red[k][wid] = s;
    }
    __syncthreads();
    if (t == 0) {
        float i_r = red[0][0] + red[0][1] + red[0][2] + red[0][3] + b_ih[r];
        float i_z = red[1][0] + red[1][1] + red[1][2] + red[1][3] + b_ih[HH + r];
        float i_n = red[2][0] + red[2][1] + red[2][2] + red[2][3] + b_ih[2 * HH + r];
        float h_r = gh[r];
        float h_z = gh[HH + r];
        float h_n = gh[2 * HH + r];
        float rg = 1.f / (1.f + expf(-(i_r + h_r)));
        float z  = 1.f / (1.f + expf(-(i_z + h_z)));
        float n  = tanhf(i_n + rg * h_n);
        h_new[r] = (1.f - z) * n + z * h[r];
    }
}

// out logits: block per row, L=4096; out_W stream-once (nt)
__global__ void k_out(const float* __restrict__ W, const float* __restrict__ xv,
                      const float* __restrict__ b, float* __restrict__ y) {
    int r = blockIdx.x;
    float acc = dot_row<4, true>((const f4*)(W + (size_t)r * HH), (const f4*)xv);
    float tot = block_sum(acc);
    if (threadIdx.x == 0) y[r] = tot + b[r];
}

// log_softmax over 4096: 16 blocks, each redundantly computes the stats
// (identical order -> identical lse) and writes its own 256-col slice.
__global__ void k_lsm(const float* __restrict__ l, float* __restrict__ out) {
    __shared__ float red[4];
    __shared__ float bval;
    int t = threadIdx.x;
    float v[16];
    float m = -INFINITY;
#pragma unroll
    for (int j = 0; j < 16; ++j) { v[j] = l[t + 256 * j]; m = fmaxf(m, v[j]); }
    m = wave_max(m);
    if ((t & 63) == 0) red[t >> 6] = m;
    __syncthreads();
    if (t == 0) bval = fmaxf(fmaxf(red[0], red[1]), fmaxf(red[2], red[3]));
    __syncthreads();
    float mx = bval;
    float s = 0.f;
#pragma unroll
    for (int j = 0; j < 16; ++j) s += expf(v[j] - mx);
    s = wave_sum(s);
    __syncthreads();
    if ((t & 63) == 0) red[t >> 6] = s;
    __syncthreads();
    if (t == 0) bval = red[0] + red[1] + red[2] + red[3];
    __syncthreads();
    float lse = mx + logf(bval);
    // thread t's value v[j] sits at index t + 256*j; block b owns j == b
    out[blockIdx.x * 256 + t] = v[blockIdx.x] - lse;
}

extern "C" void kernel_launch(void* const* d_in, const int* in_sizes, int n_in,
                              void* d_out, int out_size, void* d_ws, size_t ws_size,
                              hipStream_t stream) {
    const int*   idx     = (const int*)  d_in[0];
    const float* hidden  = (const float*)d_in[1];
    // d_in[2] (encoder_output) unused by the forward pass
    const float* enc     = (const float*)d_in[3];
    const float* emb_W   = (const float*)d_in[4];
    const float* att_W   = (const float*)d_in[5];
    const float* att_b   = (const float*)d_in[6];
    const float* atc_W   = (const float*)d_in[7];
    const float* atc_b   = (const float*)d_in[8];
    const float* W_ih    = (const float*)d_in[9];
    const float* W_hh    = (const float*)d_in[10];
    const float* b_ih    = (const float*)d_in[11];
    const float* b_hh    = (const float*)d_in[12];
    const float* out_W   = (const float*)d_in[13];
    const float* out_b   = (const float*)d_in[14];

    float* out    = (float*)d_out;        // [0, 4096)    log_softmax
    float* h_new  = out + OO;             // [4096, 8192) new hidden
    float* atw    = out + OO + HH;        // [8192,10240) attention weights

    float* ws         = (float*)d_ws;
    float* attlog     = ws;               // 2048
    float* atap       = ws + 2048;        // 4096
    float* x          = ws + 6144;        // 4096
    float* outlog     = ws + 10240;       // 4096
    float* gh         = ws + 14336;       // 12288
    float* atcemb     = ws + 26624;       // 4096

    // 1. att logits + gh + atc emb-half (fused, 18432 blocks, 1:6:2 interleave)
    k_stage1<<<9 * MAXLEN, 256, 0, stream>>>(att_W, att_b, emb_W, idx, hidden,
                                             W_hh, b_hh, atc_W, atc_b,
                                             attlog, gh, atcemb);
    // 2. fused softmax + full weighted column-sum -> atap (also writes atw)
    k_atap<<<256, 256, 0, stream>>>(attlog, enc, atap, atw);
    // 3. x = relu(atcemb + atc_W_right @ atap)
    k_atc2<<<HH, 256, 0, stream>>>(atc_W, atcemb, atap, x);
    // 4. gi + gate math -> h_new output
    k_gig<<<HH, 256, 0, stream>>>(W_ih, b_ih, x, gh, hidden, h_new);
    // 5. out logits (block per row)
    k_out<<<HH, 256, 0, stream>>>(out_W, h_new, out_b, outlog);
    // 6. log_softmax -> out (16 blocks, redundant stats)
    k_lsm<<<16, 256, 0, stream>>>(outlog, out);
}

// Round 11
// 122.126 us; speedup vs baseline: 1.0103x; 1.0103x over previous
//
#include <hip/hip_runtime.h>
#include <math.h>

#define HH 4096
#define OO 4096
#define MAXLEN 2048

typedef float f4 __attribute__((ext_vector_type(4)));

__device__ inline float wave_sum(float v) {
#pragma unroll
    for (int off = 32; off; off >>= 1) v += __shfl_down(v, off, 64);
    return v;
}
__device__ inline float wave_max(float v) {
#pragma unroll
    for (int off = 32; off; off >>= 1) v = fmaxf(v, __shfl_down(v, off, 64));
    return v;
}

// sum 256 per-thread partials; result valid in all threads
__device__ inline float block_sum(float acc) {
    __shared__ float red[4];
    acc = wave_sum(acc);
    int t = threadIdx.x;
    if ((t & 63) == 0) red[t >> 6] = acc;
    __syncthreads();
    return red[0] + red[1] + red[2] + red[3];
}

// per-thread partial dot over 1024*NV floats; 256 threads/block.
// NT: non-temporal (stream-once) hint on the W side only.
template <int NV, bool NT>
__device__ inline float dot_row(const f4* __restrict__ W4, const f4* __restrict__ x4) {
    int t = threadIdx.x;
    float acc = 0.f;
#pragma unroll
    for (int j = 0; j < NV; ++j) {
        f4 w = NT ? __builtin_nontemporal_load(W4 + t + 256 * j) : W4[t + 256 * j];
        f4 v = x4[t + 256 * j];
        acc = fmaf(w[0], v[0], acc);
        acc = fmaf(w[1], v[1], acc);
        acc = fmaf(w[2], v[2], acc);
        acc = fmaf(w[3], v[3], acc);
    }
    return acc;
}

// fused first stage, 18432 = 9*2048 blocks, interleaved 1:6:2 —
//   m==0   -> attention logit row k            (att_W nt, 2 passes)
//   m=1..6 -> gh row k*6+m-1 = W_hh·h + b_hh   (W_hh non-nt, L3-resident)
//   m=7..8 -> atcemb row k*2+m-7 = atc_W[r,:H]·emb + atc_b  (nt)
__global__ void k_stage1(const float* __restrict__ att_W, const float* __restrict__ att_b,
                         const float* __restrict__ emb_W, const int* __restrict__ idx,
                         const float* __restrict__ hidden,
                         const float* __restrict__ W_hh, const float* __restrict__ b_hh,
                         const float* __restrict__ atc_W, const float* __restrict__ atc_b,
                         float* __restrict__ attlog, float* __restrict__ gh,
                         float* __restrict__ atcemb) {
    int blk = blockIdx.x;
    int k = blk / 9, m = blk % 9;
    if (m == 0) {
        int r = k;                         // 0..2047
        const float* emb = emb_W + (size_t)idx[0] * HH;
        const float* Wr = att_W + (size_t)r * (2 * HH);
        float acc = dot_row<4, true>((const f4*)Wr, (const f4*)emb)
                  + dot_row<4, true>((const f4*)(Wr + HH), (const f4*)hidden);
        float tot = block_sum(acc);
        if (threadIdx.x == 0) attlog[r] = tot + att_b[r];
    } else if (m <= 6) {
        int r = k * 6 + (m - 1);           // 0..12287
        float acc = dot_row<4, false>((const f4*)(W_hh + (size_t)r * HH), (const f4*)hidden);
        float tot = block_sum(acc);
        if (threadIdx.x == 0) gh[r] = tot + b_hh[r];
    } else {
        int r = k * 2 + (m - 7);           // 0..4095
        const float* emb = emb_W + (size_t)idx[0] * HH;
        float acc = dot_row<4, true>((const f4*)(atc_W + (size_t)r * (2 * HH)), (const f4*)emb);
        float tot = block_sum(acc);
        if (threadIdx.x == 0) atcemb[r] = tot + atc_b[r];
    }
}

// fused softmax + weighted partial column-sums.
// 512 blocks = 128 row-chunks (16 rows) x 4 col-quarters. Each block
// redundantly computes softmax stats from attlog (8KB, cache-resident).
// q==0 blocks also write atw (the third output). enc is nt this round
// (L3 residency budget reallocated to W_ih gate-r).
__global__ void k_smpart(const float* __restrict__ attlog, const float* __restrict__ E,
                         float* __restrict__ part, float* __restrict__ atw) {
    __shared__ float red[4];
    __shared__ float s_mx, s_sum;
    int t = threadIdx.x;
    int q = blockIdx.x & 3;
    int c = blockIdx.x >> 2;              // 0..127

    float v[8];
    float m = -INFINITY;
#pragma unroll
    for (int j = 0; j < 8; ++j) { v[j] = attlog[t + 256 * j]; m = fmaxf(m, v[j]); }
    m = wave_max(m);
    if ((t & 63) == 0) red[t >> 6] = m;
    __syncthreads();
    if (t == 0) s_mx = fmaxf(fmaxf(red[0], red[1]), fmaxf(red[2], red[3]));
    __syncthreads();
    float mx = s_mx;
    float s = 0.f;
#pragma unroll
    for (int j = 0; j < 8; ++j) s += expf(v[j] - mx);
    s = wave_sum(s);
    __syncthreads();
    if ((t & 63) == 0) red[t >> 6] = s;
    __syncthreads();
    if (t == 0) s_sum = red[0] + red[1] + red[2] + red[3];
    __syncthreads();
    float inv = 1.0f / s_sum;

    int col4 = q * 256 + t;
    f4 acc = {0.f, 0.f, 0.f, 0.f};
#pragma unroll 8
    for (int rr = 0; rr < 16; ++rr) {
        int mrow = c * 16 + rr;
        float wm = expf(attlog[mrow] - mx) * inv;
        f4 e = __builtin_nontemporal_load((const f4*)(E + (size_t)mrow * HH) + col4);
        acc[0] = fmaf(wm, e[0], acc[0]);
        acc[1] = fmaf(wm, e[1], acc[1]);
        acc[2] = fmaf(wm, e[2], acc[2]);
        acc[3] = fmaf(wm, e[3], acc[3]);
    }
    ((f4*)(part + (size_t)c * HH))[col4] = acc;

    if (q == 0 && t < 16) {
        int mrow = c * 16 + t;
        atw[mrow] = expf(attlog[mrow] - mx) * inv;
    }
}

// deterministic reduce of 128 partial rows -> atap.
// 32 blocks x 256 threads; 8 threads cooperate per f4 output (16 c's each,
// c = cp + 8*i ascending -> fixed order), in-wave shfl tree (width-8 groups).
__global__ void k_red(const float* __restrict__ part, float* __restrict__ atap) {
    int t = threadIdx.x;
    int o  = blockIdx.x * 32 + (t >> 3);   // f4 output index, 0..1023
    int cp = t & 7;
    f4 s = {0.f, 0.f, 0.f, 0.f};
#pragma unroll
    for (int i = 0; i < 16; ++i) {
        f4 p = ((const f4*)part)[(size_t)(cp + 8 * i) * (HH / 4) + o];
        s[0] += p[0]; s[1] += p[1]; s[2] += p[2]; s[3] += p[3];
    }
#pragma unroll
    for (int off = 4; off; off >>= 1) {
        s[0] += __shfl_down(s[0], off, 64);
        s[1] += __shfl_down(s[1], off, 64);
        s[2] += __shfl_down(s[2], off, 64);
        s[3] += __shfl_down(s[3], off, 64);
    }
    if (cp == 0) ((f4*)atap)[o] = s;
}

// x = relu(atcemb + atc_W[r, H:2H]·atap), block per row, 16KB/block (nt)
__global__ void k_atc2(const float* __restrict__ atc_W, const float* __restrict__ atcemb,
                       const float* __restrict__ atap, float* __restrict__ x) {
    int r = blockIdx.x;
    float acc = dot_row<4, true>((const f4*)(atc_W + (size_t)r * (2 * HH) + HH),
                                 (const f4*)atap);
    float tot = block_sum(acc);
    if (threadIdx.x == 0) x[r] = fmaxf(tot + atcemb[r], 0.f);
}

// gi + gate math: block r computes 3 W_ih row-dots vs x, combines with
// precomputed gh (already includes b_hh) -> h_new[r].
// Gate-r rows (flat rows 0..4095, 64 MB) are NON-nt -> L3-resident with W_hh
// (192+64 = 256 MB set); gate-z/n rows stay nt (stream-once).
__global__ void k_gig(const float* __restrict__ W_ih, const float* __restrict__ b_ih,
                      const float* __restrict__ x, const float* __restrict__ gh,
                      const float* __restrict__ h, float* __restrict__ h_new) {
    __shared__ float red[3][4];
    int r = blockIdx.x;
    int t = threadIdx.x, wid = t >> 6, lane = t & 63;
    const f4* xv = (const f4*)x;
    float a[3];
    a[0] = dot_row<4, false>((const f4*)(W_ih + (size_t)r * HH), xv);
    a[1] = dot_row<4, true >((const f4*)(W_ih + (size_t)(HH + r) * HH), xv);
    a[2] = dot_row<4, true >((const f4*)(W_ih + (size_t)(2 * HH + r) * HH), xv);
#pragma unroll
    for (int k = 0; k < 3; ++k) {
        float s = wave_sum(a[k]);
        if (lane == 0) red[k][wid] = s;
    }
    __syncthreads();
    if (t == 0) {
        float i_r = red[0][0] + red[0][1] + red[0][2] + red[0][3] + b_ih[r];
        float i_z = red[1][0] + red[1][1] + red[1][2] + red[1][3] + b_ih[HH + r];
        float i_n = red[2][0] + red[2][1] + red[2][2] + red[2][3] + b_ih[2 * HH + r];
        float h_r = gh[r];
        float h_z = gh[HH + r];
        float h_n = gh[2 * HH + r];
        float rg = 1.f / (1.f + expf(-(i_r + h_r)));
        float z  = 1.f / (1.f + expf(-(i_z + h_z)));
        float n  = tanhf(i_n + rg * h_n);
        h_new[r] = (1.f - z) * n + z * h[r];
    }
}

// out logits: block per row, L=4096; out_W stream-once (nt)
__global__ void k_out(const float* __restrict__ W, const float* __restrict__ xv,
                      const float* __restrict__ b, float* __restrict__ y) {
    int r = blockIdx.x;
    float acc = dot_row<4, true>((const f4*)(W + (size_t)r * HH), (const f4*)xv);
    float tot = block_sum(acc);
    if (threadIdx.x == 0) y[r] = tot + b[r];
}

// log_softmax over 4096: 16 blocks, each redundantly computes the stats
// (identical order -> identical lse) and writes its own 256-col slice.
__global__ void k_lsm(const float* __restrict__ l, float* __restrict__ out) {
    __shared__ float red[4];
    __shared__ float bval;
    int t = threadIdx.x;
    float v[16];
    float m = -INFINITY;
#pragma unroll
    for (int j = 0; j < 16; ++j) { v[j] = l[t + 256 * j]; m = fmaxf(m, v[j]); }
    m = wave_max(m);
    if ((t & 63) == 0) red[t >> 6] = m;
    __syncthreads();
    if (t == 0) bval = fmaxf(fmaxf(red[0], red[1]), fmaxf(red[2], red[3]));
    __syncthreads();
    float mx = bval;
    float s = 0.f;
#pragma unroll
    for (int j = 0; j < 16; ++j) s += expf(v[j] - mx);
    s = wave_sum(s);
    __syncthreads();
    if ((t & 63) == 0) red[t >> 6] = s;
    __syncthreads();
    if (t == 0) bval = red[0] + red[1] + red[2] + red[3];
    __syncthreads();
    float lse = mx + logf(bval);
    // thread t's value v[j] sits at index t + 256*j; block b owns j == b
    out[blockIdx.x * 256 + t] = v[blockIdx.x] - lse;
}

extern "C" void kernel_launch(void* const* d_in, const int* in_sizes, int n_in,
                              void* d_out, int out_size, void* d_ws, size_t ws_size,
                              hipStream_t stream) {
    const int*   idx     = (const int*)  d_in[0];
    const float* hidden  = (const float*)d_in[1];
    // d_in[2] (encoder_output) unused by the forward pass
    const float* enc     = (const float*)d_in[3];
    const float* emb_W   = (const float*)d_in[4];
    const float* att_W   = (const float*)d_in[5];
    const float* att_b   = (const float*)d_in[6];
    const float* atc_W   = (const float*)d_in[7];
    const float* atc_b   = (const float*)d_in[8];
    const float* W_ih    = (const float*)d_in[9];
    const float* W_hh    = (const float*)d_in[10];
    const float* b_ih    = (const float*)d_in[11];
    const float* b_hh    = (const float*)d_in[12];
    const float* out_W   = (const float*)d_in[13];
    const float* out_b   = (const float*)d_in[14];

    float* out    = (float*)d_out;        // [0, 4096)    log_softmax
    float* h_new  = out + OO;             // [4096, 8192) new hidden
    float* atw    = out + OO + HH;        // [8192,10240) attention weights

    float* ws         = (float*)d_ws;
    float* attlog     = ws;               // 2048
    float* atap       = ws + 2048;        // 4096
    float* x          = ws + 6144;        // 4096
    float* outlog     = ws + 10240;       // 4096
    float* gh         = ws + 14336;       // 12288
    float* atcemb     = ws + 26624;       // 4096
    float* part       = ws + 30720;       // 128*4096

    // 1. att logits + gh + atc emb-half (fused, 18432 blocks, 1:6:2 interleave)
    k_stage1<<<9 * MAXLEN, 256, 0, stream>>>(att_W, att_b, emb_W, idx, hidden,
                                             W_hh, b_hh, atc_W, atc_b,
                                             attlog, gh, atcemb);
    // 2. fused softmax + weighted partial column-sums (also writes atw output)
    k_smpart<<<512, 256, 0, stream>>>(attlog, enc, part, atw);
    // 3. deterministic wide reduce -> atap (f4 loads, 8 thr/output)
    k_red<<<32, 256, 0, stream>>>(part, atap);
    // 4. x = relu(atcemb + atc_W_right @ atap)
    k_atc2<<<HH, 256, 0, stream>>>(atc_W, atcemb, atap, x);
    // 5. gi + gate math -> h_new output (W_ih gate-r L3-resident)
    k_gig<<<HH, 256, 0, stream>>>(W_ih, b_ih, x, gh, hidden, h_new);
    // 6. out logits (block per row)
    k_out<<<HH, 256, 0, stream>>>(out_W, h_new, out_b, outlog);
    // 7. log_softmax -> out (16 blocks, redundant stats)
    k_lsm<<<16, 256, 0, stream>>>(outlog, out);
}

// Round 12
// 122.006 us; speedup vs baseline: 1.0113x; 1.0010x over previous
//
#include <hip/hip_runtime.h>
#include <math.h>

#define HH 4096
#define OO 4096
#define MAXLEN 2048

typedef float f4 __attribute__((ext_vector_type(4)));

__device__ inline float wave_sum(float v) {
#pragma unroll
    for (int off = 32; off; off >>= 1) v += __shfl_down(v, off, 64);
    return v;
}
__device__ inline float wave_max(float v) {
#pragma unroll
    for (int off = 32; off; off >>= 1) v = fmaxf(v, __shfl_down(v, off, 64));
    return v;
}

// sum 256 per-thread partials; result valid in all threads
__device__ inline float block_sum(float acc) {
    __shared__ float red[4];
    acc = wave_sum(acc);
    int t = threadIdx.x;
    if ((t & 63) == 0) red[t >> 6] = acc;
    __syncthreads();
    return red[0] + red[1] + red[2] + red[3];
}

// per-thread partial dot over 1024*NV floats; 256 threads/block.
// NT: non-temporal (stream-once) hint on the W side only.
template <int NV, bool NT>
__device__ inline float dot_row(const f4* __restrict__ W4, const f4* __restrict__ x4) {
    int t = threadIdx.x;
    float acc = 0.f;
#pragma unroll
    for (int j = 0; j < NV; ++j) {
        f4 w = NT ? __builtin_nontemporal_load(W4 + t + 256 * j) : W4[t + 256 * j];
        f4 v = x4[t + 256 * j];
        acc = fmaf(w[0], v[0], acc);
        acc = fmaf(w[1], v[1], acc);
        acc = fmaf(w[2], v[2], acc);
        acc = fmaf(w[3], v[3], acc);
    }
    return acc;
}

// fused first stage, 18432 = 9*2048 blocks, interleaved 1:6:2 —
//   m==0   -> attention logit row k            (att_W nt, 2 passes)
//   m=1..6 -> gh row k*6+m-1 = W_hh·h + b_hh   (W_hh non-nt, L3-resident)
//   m=7..8 -> atcemb row k*2+m-7 = atc_W[r,:H]·emb + atc_b  (nt)
__global__ void k_stage1(const float* __restrict__ att_W, const float* __restrict__ att_b,
                         const float* __restrict__ emb_W, const int* __restrict__ idx,
                         const float* __restrict__ hidden,
                         const float* __restrict__ W_hh, const float* __restrict__ b_hh,
                         const float* __restrict__ atc_W, const float* __restrict__ atc_b,
                         float* __restrict__ attlog, float* __restrict__ gh,
                         float* __restrict__ atcemb) {
    int blk = blockIdx.x;
    int k = blk / 9, m = blk % 9;
    if (m == 0) {
        int r = k;                         // 0..2047
        const float* emb = emb_W + (size_t)idx[0] * HH;
        const float* Wr = att_W + (size_t)r * (2 * HH);
        float acc = dot_row<4, true>((const f4*)Wr, (const f4*)emb)
                  + dot_row<4, true>((const f4*)(Wr + HH), (const f4*)hidden);
        float tot = block_sum(acc);
        if (threadIdx.x == 0) attlog[r] = tot + att_b[r];
    } else if (m <= 6) {
        int r = k * 6 + (m - 1);           // 0..12287
        float acc = dot_row<4, false>((const f4*)(W_hh + (size_t)r * HH), (const f4*)hidden);
        float tot = block_sum(acc);
        if (threadIdx.x == 0) gh[r] = tot + b_hh[r];
    } else {
        int r = k * 2 + (m - 7);           // 0..4095
        const float* emb = emb_W + (size_t)idx[0] * HH;
        float acc = dot_row<4, true>((const f4*)(atc_W + (size_t)r * (2 * HH)), (const f4*)emb);
        float tot = block_sum(acc);
        if (threadIdx.x == 0) atcemb[r] = tot + atc_b[r];
    }
}

// fused softmax + weighted partial column-sums.
// 512 blocks = 128 row-chunks (16 rows) x 4 col-quarters. Each block
// redundantly computes softmax stats from attlog (8KB, cache-resident).
// q==0 blocks also write atw (the third output). enc NON-nt (L3-resident set,
// R9-proven config).
__global__ void k_smpart(const float* __restrict__ attlog, const float* __restrict__ E,
                         float* __restrict__ part, float* __restrict__ atw) {
    __shared__ float red[4];
    __shared__ float s_mx, s_sum;
    int t = threadIdx.x;
    int q = blockIdx.x & 3;
    int c = blockIdx.x >> 2;              // 0..127

    float v[8];
    float m = -INFINITY;
#pragma unroll
    for (int j = 0; j < 8; ++j) { v[j] = attlog[t + 256 * j]; m = fmaxf(m, v[j]); }
    m = wave_max(m);
    if ((t & 63) == 0) red[t >> 6] = m;
    __syncthreads();
    if (t == 0) s_mx = fmaxf(fmaxf(red[0], red[1]), fmaxf(red[2], red[3]));
    __syncthreads();
    float mx = s_mx;
    float s = 0.f;
#pragma unroll
    for (int j = 0; j < 8; ++j) s += expf(v[j] - mx);
    s = wave_sum(s);
    __syncthreads();
    if ((t & 63) == 0) red[t >> 6] = s;
    __syncthreads();
    if (t == 0) s_sum = red[0] + red[1] + red[2] + red[3];
    __syncthreads();
    float inv = 1.0f / s_sum;

    int col4 = q * 256 + t;
    f4 acc = {0.f, 0.f, 0.f, 0.f};
#pragma unroll 8
    for (int rr = 0; rr < 16; ++rr) {
        int mrow = c * 16 + rr;
        float wm = expf(attlog[mrow] - mx) * inv;
        f4 e = ((const f4*)(E + (size_t)mrow * HH))[col4];
        acc[0] = fmaf(wm, e[0], acc[0]);
        acc[1] = fmaf(wm, e[1], acc[1]);
        acc[2] = fmaf(wm, e[2], acc[2]);
        acc[3] = fmaf(wm, e[3], acc[3]);
    }
    ((f4*)(part + (size_t)c * HH))[col4] = acc;

    if (q == 0 && t < 16) {
        int mrow = c * 16 + t;
        atw[mrow] = expf(attlog[mrow] - mx) * inv;
    }
}

// deterministic reduce of 128 partial rows -> atap.
// 32 blocks x 256 threads; 8 threads cooperate per f4 output (16 c's each,
// c = cp + 8*i ascending -> fixed order), in-wave shfl tree (width-8 groups).
__global__ void k_red(const float* __restrict__ part, float* __restrict__ atap) {
    int t = threadIdx.x;
    int o  = blockIdx.x * 32 + (t >> 3);   // f4 output index, 0..1023
    int cp = t & 7;
    f4 s = {0.f, 0.f, 0.f, 0.f};
#pragma unroll
    for (int i = 0; i < 16; ++i) {
        f4 p = ((const f4*)part)[(size_t)(cp + 8 * i) * (HH / 4) + o];
        s[0] += p[0]; s[1] += p[1]; s[2] += p[2]; s[3] += p[3];
    }
#pragma unroll
    for (int off = 4; off; off >>= 1) {
        s[0] += __shfl_down(s[0], off, 64);
        s[1] += __shfl_down(s[1], off, 64);
        s[2] += __shfl_down(s[2], off, 64);
        s[3] += __shfl_down(s[3], off, 64);
    }
    if (cp == 0) ((f4*)atap)[o] = s;
}

// x = relu(atcemb + atc_W[r, H:2H]·atap); 2048 blocks x 2 sequential rows
// (single residency round: 8 blocks/CU x 256 CUs)
__global__ void k_atc2(const float* __restrict__ atc_W, const float* __restrict__ atcemb,
                       const float* __restrict__ atap, float* __restrict__ x) {
#pragma unroll 1
    for (int rr = 0; rr < 2; ++rr) {
        int r = blockIdx.x * 2 + rr;
        float acc = dot_row<4, true>((const f4*)(atc_W + (size_t)r * (2 * HH) + HH),
                                     (const f4*)atap);
        float tot = block_sum(acc);
        if (threadIdx.x == 0) x[r] = fmaxf(tot + atcemb[r], 0.f);
        __syncthreads();                  // red reuse across rows
    }
}

// gi + gate math; 2048 blocks x 2 sequential rows (single residency round).
// Per row: 3 W_ih row-dots vs x (all nt, R9 config), combine with gh.
__global__ void k_gig(const float* __restrict__ W_ih, const float* __restrict__ b_ih,
                      const float* __restrict__ x, const float* __restrict__ gh,
                      const float* __restrict__ h, float* __restrict__ h_new) {
    __shared__ float red[3][4];
    int t = threadIdx.x, wid = t >> 6, lane = t & 63;
    const f4* xv = (const f4*)x;
#pragma unroll 1
    for (int rr = 0; rr < 2; ++rr) {
        int r = blockIdx.x * 2 + rr;
        float a[3];
        a[0] = dot_row<4, true>((const f4*)(W_ih + (size_t)r * HH), xv);
        a[1] = dot_row<4, true>((const f4*)(W_ih + (size_t)(HH + r) * HH), xv);
        a[2] = dot_row<4, true>((const f4*)(W_ih + (size_t)(2 * HH + r) * HH), xv);
#pragma unroll
        for (int k = 0; k < 3; ++k) {
            float s = wave_sum(a[k]);
            if (lane == 0) red[k][wid] = s;
        }
        __syncthreads();
        if (t == 0) {
            float i_r = red[0][0] + red[0][1] + red[0][2] + red[0][3] + b_ih[r];
            float i_z = red[1][0] + red[1][1] + red[1][2] + red[1][3] + b_ih[HH + r];
            float i_n = red[2][0] + red[2][1] + red[2][2] + red[2][3] + b_ih[2 * HH + r];
            float h_r = gh[r];
            float h_z = gh[HH + r];
            float h_n = gh[2 * HH + r];
            float rg = 1.f / (1.f + expf(-(i_r + h_r)));
            float z  = 1.f / (1.f + expf(-(i_z + h_z)));
            float n  = tanhf(i_n + rg * h_n);
            h_new[r] = (1.f - z) * n + z * h[r];
        }
        __syncthreads();                  // red reuse across rows
    }
}

// out logits; 2048 blocks x 2 sequential rows (single residency round), nt
__global__ void k_out(const float* __restrict__ W, const float* __restrict__ xv,
                      const float* __restrict__ b, float* __restrict__ y) {
#pragma unroll 1
    for (int rr = 0; rr < 2; ++rr) {
        int r = blockIdx.x * 2 + rr;
        float acc = dot_row<4, true>((const f4*)(W + (size_t)r * HH), (const f4*)xv);
        float tot = block_sum(acc);
        if (threadIdx.x == 0) y[r] = tot + b[r];
        __syncthreads();                  // red reuse across rows
    }
}

// log_softmax over 4096: 16 blocks, each redundantly computes the stats
// (identical order -> identical lse) and writes its own 256-col slice.
__global__ void k_lsm(const float* __restrict__ l, float* __restrict__ out) {
    __shared__ float red[4];
    __shared__ float bval;
    int t = threadIdx.x;
    float v[16];
    float m = -INFINITY;
#pragma unroll
    for (int j = 0; j < 16; ++j) { v[j] = l[t + 256 * j]; m = fmaxf(m, v[j]); }
    m = wave_max(m);
    if ((t & 63) == 0) red[t >> 6] = m;
    __syncthreads();
    if (t == 0) bval = fmaxf(fmaxf(red[0], red[1]), fmaxf(red[2], red[3]));
    __syncthreads();
    float mx = bval;
    float s = 0.f;
#pragma unroll
    for (int j = 0; j < 16; ++j) s += expf(v[j] - mx);
    s = wave_sum(s);
    __syncthreads();
    if ((t & 63) == 0) red[t >> 6] = s;
    __syncthreads();
    if (t == 0) bval = red[0] + red[1] + red[2] + red[3];
    __syncthreads();
    float lse = mx + logf(bval);
    // thread t's value v[j] sits at index t + 256*j; block b owns j == b
    out[blockIdx.x * 256 + t] = v[blockIdx.x] - lse;
}

extern "C" void kernel_launch(void* const* d_in, const int* in_sizes, int n_in,
                              void* d_out, int out_size, void* d_ws, size_t ws_size,
                              hipStream_t stream) {
    const int*   idx     = (const int*)  d_in[0];
    const float* hidden  = (const float*)d_in[1];
    // d_in[2] (encoder_output) unused by the forward pass
    const float* enc     = (const float*)d_in[3];
    const float* emb_W   = (const float*)d_in[4];
    const float* att_W   = (const float*)d_in[5];
    const float* att_b   = (const float*)d_in[6];
    const float* atc_W   = (const float*)d_in[7];
    const float* atc_b   = (const float*)d_in[8];
    const float* W_ih    = (const float*)d_in[9];
    const float* W_hh    = (const float*)d_in[10];
    const float* b_ih    = (const float*)d_in[11];
    const float* b_hh    = (const float*)d_in[12];
    const float* out_W   = (const float*)d_in[13];
    const float* out_b   = (const float*)d_in[14];

    float* out    = (float*)d_out;        // [0, 4096)    log_softmax
    float* h_new  = out + OO;             // [4096, 8192) new hidden
    float* atw    = out + OO + HH;        // [8192,10240) attention weights

    float* ws         = (float*)d_ws;
    float* attlog     = ws;               // 2048
    float* atap       = ws + 2048;        // 4096
    float* x          = ws + 6144;        // 4096
    float* outlog     = ws + 10240;       // 4096
    float* gh         = ws + 14336;       // 12288
    float* atcemb     = ws + 26624;       // 4096
    float* part       = ws + 30720;       // 128*4096

    // 1. att logits + gh + atc emb-half (fused, 18432 blocks, 1:6:2 interleave)
    k_stage1<<<9 * MAXLEN, 256, 0, stream>>>(att_W, att_b, emb_W, idx, hidden,
                                             W_hh, b_hh, atc_W, atc_b,
                                             attlog, gh, atcemb);
    // 2. fused softmax + weighted partial column-sums (also writes atw output)
    k_smpart<<<512, 256, 0, stream>>>(attlog, enc, part, atw);
    // 3. deterministic wide reduce -> atap (f4 loads, 8 thr/output)
    k_red<<<32, 256, 0, stream>>>(part, atap);
    // 4. x = relu(atcemb + atc_W_right @ atap)  [2048 blocks, 1 round]
    k_atc2<<<HH / 2, 256, 0, stream>>>(atc_W, atcemb, atap, x);
    // 5. gi + gate math -> h_new output         [2048 blocks, 1 round]
    k_gig<<<HH / 2, 256, 0, stream>>>(W_ih, b_ih, x, gh, hidden, h_new);
    // 6. out logits                              [2048 blocks, 1 round]
    k_out<<<HH / 2, 256, 0, stream>>>(out_W, h_new, out_b, outlog);
    // 7. log_softmax -> out (16 blocks, redundant stats)
    k_lsm<<<16, 256, 0, stream>>>(outlog, out);
}